// Round 4
// baseline (270.096 us; speedup 1.0000x reference)
//
#include <hip/hip_runtime.h>
#include <hip/hip_bf16.h>

// Problem constants
#define T_ 8192
#define H_ 64
#define X_ 128
#define C_ 128   // chunks
#define L_ 64    // chunk length
#define NB 512   // grid blocks; co-residency guaranteed by __launch_bounds__(256,2)
#define MS 68    // LDS matrix row stride (floats)

// workspace layout (float offsets)
#define OFF_BT8 (T_ * H_)
#define OFF_A2  (2 * T_ * H_)
#define OFF_A4  (OFF_A2 + 4096)
#define OFF_A8  (OFF_A4 + 4096)
#define OFF_Q   (OFF_A8 + 4096)
#define OFF_Q8  (OFF_Q + 4096)
#define OFF_V   (OFF_Q8 + 4096)
#define OFF_VT  (OFF_V + C_ * H_)
#define OFF_HS  (OFF_VT + C_ * H_)
#define OFF_CNT (OFF_HS + C_ * H_)   // barrier counters (16 u32)

// ---------------------------------------------------------------------------
__device__ __forceinline__ float bcast(float v, int src) {
    return __int_as_float(__builtin_amdgcn_readlane(__float_as_int(v), src));
}

// newh[i] = sum_j arow[j]*h[j] + b_i ; h lane-distributed, arow in registers.
__device__ __forceinline__ float lru_step(const float* arow, float h, float b_i) {
    float a0 = b_i, a1 = 0.f, a2 = 0.f, a3 = 0.f;
#pragma unroll
    for (int j = 0; j < 16; ++j) {
        a0 = fmaf(arow[j],      bcast(h, j),      a0);
        a1 = fmaf(arow[j + 16], bcast(h, j + 16), a1);
        a2 = fmaf(arow[j + 32], bcast(h, j + 32), a2);
        a3 = fmaf(arow[j + 48], bcast(h, j + 48), a3);
    }
    return (a0 + a1) + (a2 + a3);
}

__device__ __forceinline__ void pin_row(float* arow) {
#pragma unroll
    for (int q = 0; q < 64; ++q) asm volatile("" : "+v"(arow[q]));
}

__device__ __forceinline__ void load_arow_A(const float* __restrict__ A_raw,
                                            int lane, float* arow) {
    const float4* a4 = (const float4*)(A_raw + lane * H_);
#pragma unroll
    for (int q = 0; q < 16; ++q) {
        float4 t4 = a4[q];
        arow[4 * q + 0] = 0.1f * t4.x;
        arow[4 * q + 1] = 0.1f * t4.y;
        arow[4 * q + 2] = 0.1f * t4.z;
        arow[4 * q + 3] = 0.1f * t4.w;
    }
#pragma unroll
    for (int q = 0; q < 64; ++q) arow[q] += (q == lane) ? 0.9f : 0.0f;
    pin_row(arow);
}

__device__ __forceinline__ void load_row(const float* __restrict__ M,
                                         int lane, float* arow) {
    const float4* a4 = (const float4*)(M + lane * H_);
#pragma unroll
    for (int q = 0; q < 16; ++q) {
        float4 t4 = a4[q];
        arow[4 * q + 0] = t4.x;
        arow[4 * q + 1] = t4.y;
        arow[4 * q + 2] = t4.z;
        arow[4 * q + 3] = t4.w;
    }
    pin_row(arow);
}

// ---------------------------------------------------------------------------
// Software grid barrier. Co-residency of all NB blocks is guaranteed by
// __launch_bounds__(256,2) (VGPR<=256) + LDS 34.8KB -> >=2 blocks/CU.
// Block's writes reach its XCD L2 at __syncthreads (vmcnt drain); thread0's
// __threadfence (agent scope) writes back / invalidates for cross-XCD vis.
__device__ __forceinline__ void gsync(unsigned* cnt, int phase) {
    __syncthreads();
    if (threadIdx.x == 0) {
        __threadfence();
        __hip_atomic_fetch_add(&cnt[phase], 1u, __ATOMIC_ACQ_REL,
                               __HIP_MEMORY_SCOPE_AGENT);
        while (__hip_atomic_load(&cnt[phase], __ATOMIC_RELAXED,
                                 __HIP_MEMORY_SCOPE_AGENT) < (unsigned)NB)
            __builtin_amdgcn_s_sleep(2);
        __threadfence();
    }
    __syncthreads();
}

// ---------------------------------------------------------------------------
// Block-wide 64x64 squaring in LDS: Mout = Min*Min (Min!=Mout), optional
// global store. 256 threads: r=tid>>2 (row), 16 cols per thread.
__device__ __forceinline__ void sq64(const float* Min, float* Mout, float* gout) {
    const int tid = threadIdx.x;
    const int r = tid >> 2, c0 = (tid & 3) * 16;
    float acc[16];
#pragma unroll
    for (int j = 0; j < 16; ++j) acc[j] = 0.f;
    for (int k = 0; k < H_; ++k) {
        const float a = Min[r * MS + k];
        const float4* b4 = (const float4*)(Min + k * MS + c0);
#pragma unroll
        for (int j4 = 0; j4 < 4; ++j4) {
            float4 bv = b4[j4];
            acc[4 * j4 + 0] = fmaf(a, bv.x, acc[4 * j4 + 0]);
            acc[4 * j4 + 1] = fmaf(a, bv.y, acc[4 * j4 + 1]);
            acc[4 * j4 + 2] = fmaf(a, bv.z, acc[4 * j4 + 2]);
            acc[4 * j4 + 3] = fmaf(a, bv.w, acc[4 * j4 + 3]);
        }
    }
#pragma unroll
    for (int j = 0; j < 16; ++j) Mout[r * MS + c0 + j] = acc[j];
    if (gout) {
#pragma unroll
        for (int j = 0; j < 16; ++j) gout[r * H_ + c0 + j] = acc[j];
    }
    __syncthreads();
}

// ---------------------------------------------------------------------------
// b-projection: 4 rows per lane-group (round-2 proven form).
__device__ __forceinline__ void bproj_rows4(const float* __restrict__ x,
                                            const float* __restrict__ B,
                                            const float* __restrict__ c,
                                            float* __restrict__ bws,
                                            int t0, int lane) {
    const float cc = c[lane];
    float acc[4] = {cc, cc, cc, cc};
    const float* Brow = B + lane * X_;
#pragma unroll
    for (int kc = 0; kc < 4; ++kc) {
        float4 br[8];
        const float4* b4 = (const float4*)(Brow + kc * 32);
#pragma unroll
        for (int q = 0; q < 8; ++q) br[q] = b4[q];
#pragma unroll
        for (int r = 0; r < 4; ++r) {
            const float4* xr = (const float4*)(x + (size_t)(t0 + r) * X_ + kc * 32);
#pragma unroll
            for (int q = 0; q < 8; ++q) {
                float4 xv = xr[q];
                acc[r] = fmaf(br[q].x, xv.x, acc[r]);
                acc[r] = fmaf(br[q].y, xv.y, acc[r]);
                acc[r] = fmaf(br[q].z, xv.z, acc[r]);
                acc[r] = fmaf(br[q].w, xv.w, acc[r]);
            }
        }
    }
#pragma unroll
    for (int r = 0; r < 4; ++r) bws[(size_t)(t0 + r) * H_ + lane] = acc[r];
}

__device__ __forceinline__ void bproj_row1(const float* __restrict__ x,
                                           const float* __restrict__ B,
                                           const float* __restrict__ c,
                                           float* __restrict__ bws,
                                           int t, int lane) {
    float acc = c[lane];
    const float4* Br = (const float4*)(B + lane * X_);
    const float4* xr = (const float4*)(x + (size_t)t * X_);
#pragma unroll
    for (int q = 0; q < 32; ++q) {
        float4 bv = Br[q];
        float4 xv = xr[q];
        acc = fmaf(bv.x, xv.x, acc);
        acc = fmaf(bv.y, xv.y, acc);
        acc = fmaf(bv.z, xv.z, acc);
        acc = fmaf(bv.w, xv.w, acc);
    }
    bws[(size_t)t * H_ + lane] = acc;
}

// ---------------------------------------------------------------------------
#define KB_ROWS 39  // 32 output rows + 7 halo

__global__ __launch_bounds__(256, 2) void lru_mega(
        const float* __restrict__ x, const float* __restrict__ h0,
        const float* __restrict__ A_raw, const float* __restrict__ B,
        const float* __restrict__ c, float* __restrict__ out,
        float* __restrict__ ws, unsigned* __restrict__ cnt) {
    __shared__ __align__(16) float smem[2 * H_ * MS];  // 34816 B, phase-unioned
    float* M1 = smem;
    float* M2 = smem + H_ * MS;

    const int tid = threadIdx.x, lane = tid & 63, w = tid >> 6;
    const int b = blockIdx.x;

    float* bws    = ws;
    float* bt8    = ws + OFF_BT8;
    float* A2g    = ws + OFF_A2;
    float* A4g    = ws + OFF_A4;
    float* A8g    = ws + OFF_A8;
    float* Qg     = ws + OFF_Q;
    float* Q8g    = ws + OFF_Q8;
    float* v      = ws + OFF_V;
    float* vt     = ws + OFF_VT;
    float* hstart = ws + OFF_HS;

    // ======================= P0: bproj || {A2, A4} =========================
    if (b < 511) {
        bproj_rows4(x, B, c, bws, b * 16 + w * 4, lane);
        if (b < 16 && w == 0) bproj_row1(x, B, c, bws, 8176 + b, lane);
    } else {
        for (int idx = tid; idx < H_ * H_; idx += 256) {
            const int r = idx >> 6, cc2 = idx & 63;
            M1[r * MS + cc2] = 0.1f * A_raw[idx] + ((r == cc2) ? 0.9f : 0.0f);
        }
        __syncthreads();
        sq64(M1, M2, A2g);   // A^2
        sq64(M2, M1, A4g);   // A^4  (stays in M1)
    }
    gsync(cnt, 0);

    // ================== P1: btilde (b<256) || {A8..A64} ====================
    if (b < 256) {
        float* buf0 = smem;
        float* buf1 = smem + KB_ROWS * H_;
        const int t0 = b * 32;
        for (int idx = tid; idx < KB_ROWS * H_; idx += 256) {
            const int row = idx >> 6;
            const int t = t0 - 7 + row;
            buf0[idx] = (t >= 0) ? bws[(size_t)t * H_ + (idx & 63)] : 0.f;
        }
        __syncthreads();
        float* srcb = buf0; float* dstb = buf1;
        float arow[64];
#pragma unroll
        for (int pass = 0; pass < 3; ++pass) {
            const int dist = 1 << pass;
            if (pass == 0)      load_arow_A(A_raw, lane, arow);
            else if (pass == 1) load_row(A2g, lane, arow);
            else                load_row(A4g, lane, arow);
            for (int row = w; row < KB_ROWS; row += 4) {
                const int t = t0 - 7 + row;
                float val = srcb[row * H_ + lane];
                if (row >= dist && t >= 0 && (t & 63) >= dist) {
                    const float4* h4 = (const float4*)(srcb + (row - dist) * H_);
                    float a0 = val, a1 = 0.f, a2 = 0.f, a3 = 0.f;
#pragma unroll
                    for (int qq = 0; qq < 16; ++qq) {
                        float4 hv = h4[qq];
                        a0 = fmaf(arow[4 * qq + 0], hv.x, a0);
                        a1 = fmaf(arow[4 * qq + 1], hv.y, a1);
                        a2 = fmaf(arow[4 * qq + 2], hv.z, a2);
                        a3 = fmaf(arow[4 * qq + 3], hv.w, a3);
                    }
                    val = (a0 + a1) + (a2 + a3);
                }
                dstb[row * H_ + lane] = val;
            }
            __syncthreads();
            float* tmp = srcb; srcb = dstb; dstb = tmp;
        }
        for (int r2 = w; r2 < 32; r2 += 4)
            bt8[(size_t)(t0 + r2) * H_ + lane] = srcb[(7 + r2) * H_ + lane];
    } else if (b == 511) {
        sq64(M1, M2, A8g);       // A^8
        sq64(M2, M1, nullptr);   // A^16
        sq64(M1, M2, nullptr);   // A^32
        sq64(M2, M1, Qg);        // A^64 = Q  (stays in M1)
    }
    gsync(cnt, 1);

    // ============== P2: v_c (128 wave-jobs) || {A128..A512} ================
    {
        const int gw = b * 4 + w;
        if (gw < C_) {
            float arow[64];
            load_row(A8g, lane, arow);
            const float* bc = bt8 + (size_t)gw * L_ * H_;
            float y = bc[7 * H_ + lane];
#pragma unroll
            for (int k = 1; k <= 7; ++k)
                y = lru_step(arow, y, bc[(size_t)(7 + 8 * k) * H_ + lane]);
            v[gw * H_ + lane] = y;
        } else if (b == 511) {
            sq64(M1, M2, nullptr);   // A^128
            sq64(M2, M1, nullptr);   // A^256
            sq64(M1, M2, Q8g);       // A^512 = Q^8
        }
    }
    gsync(cnt, 2);

    // ======================= P3: vt_c (120 wave-jobs) ======================
    {
        const int gw = b * 4 + w;
        if (gw < C_ - 8) {
            const int cc2 = gw + 8;
            float arow[64];
            load_row(Qg, lane, arow);
            float y = v[(cc2 - 8) * H_ + lane];
#pragma unroll
            for (int k = 7; k >= 1; --k)
                y = lru_step(arow, y, v[(cc2 - k) * H_ + lane]);
            vt[cc2 * H_ + lane] = y;
        }
    }
    gsync(cnt, 3);

    // ================== P4: chunk scan -> hstart (block 0) =================
    if (b == 0) {
        float* s8 = smem;  // [8][64]
        float arow8[64];
        load_row(Q8g, lane, arow8);
        if (w == 0) {
            float arowQ[64];
            load_row(Qg, lane, arowQ);
            float s = h0[lane];
            hstart[lane] = s;
            s8[lane] = s;
#pragma unroll
            for (int cc2 = 0; cc2 < 7; ++cc2) {
                s = lru_step(arowQ, s, v[cc2 * H_ + lane]);
                hstart[(cc2 + 1) * H_ + lane] = s;
                s8[(cc2 + 1) * H_ + lane] = s;
            }
        }
        __syncthreads();
        const int r0 = w, r1 = w + 4;
        float y0 = s8[r0 * H_ + lane], y1 = s8[r1 * H_ + lane];
#pragma unroll
        for (int k = 1; k <= 15; ++k) {
            const int c0 = r0 + 8 * k, c1 = r1 + 8 * k;
            y0 = lru_step(arow8, y0, vt[c0 * H_ + lane]);
            y1 = lru_step(arow8, y1, vt[c1 * H_ + lane]);
            hstart[c0 * H_ + lane] = y0;
            hstart[c1 * H_ + lane] = y1;
        }
    }
    gsync(cnt, 4);

    // ================= P5: expand chunks (blocks 0..127) ===================
    if (b < C_) {
        float* h8 = smem;  // [8][64]
        float arow8[64];
        load_row(A8g, lane, arow8);
        float* oc = out + (size_t)b * L_ * H_;
        if (w == 0) {
            float arowA[64];
            load_arow_A(A_raw, lane, arowA);
            float y = hstart[b * H_ + lane];
#pragma unroll
            for (int i = 0; i < 8; ++i) {
                y = lru_step(arowA, y, bws[((size_t)b * L_ + i) * H_ + lane]);
                oc[(size_t)i * H_ + lane] = y;
                h8[i * H_ + lane] = y;
            }
        }
        __syncthreads();
        const int r0 = w, r1 = w + 4;
        float y0 = h8[r0 * H_ + lane], y1 = h8[r1 * H_ + lane];
#pragma unroll
        for (int k = 1; k <= 7; ++k) {
            const int i0 = r0 + 8 * k, i1 = r1 + 8 * k;
            y0 = lru_step(arow8, y0, bt8[((size_t)b * L_ + i0) * H_ + lane]);
            y1 = lru_step(arow8, y1, bt8[((size_t)b * L_ + i1) * H_ + lane]);
            oc[(size_t)i0 * H_ + lane] = y0;
            oc[(size_t)i1 * H_ + lane] = y1;
        }
    }
}

extern "C" void kernel_launch(void* const* d_in, const int* in_sizes, int n_in,
                              void* d_out, int out_size, void* d_ws, size_t ws_size,
                              hipStream_t stream) {
    const float* x     = (const float*)d_in[0];  // [T, X]
    const float* h0    = (const float*)d_in[1];  // [H]
    const float* A_raw = (const float*)d_in[2];  // [H, H]
    const float* B     = (const float*)d_in[3];  // [H, X]
    const float* c     = (const float*)d_in[4];  // [H]
    float* out = (float*)d_out;                  // [T, H]
    float* ws  = (float*)d_ws;
    unsigned* cnt = (unsigned*)(ws + OFF_CNT);

    hipMemsetAsync(cnt, 0, 64, stream);
    lru_mega<<<NB, 256, 0, stream>>>(x, h0, A_raw, B, c, out, ws, cnt);
}

// Round 6
// 148.850 us; speedup vs baseline: 1.8146x; 1.8146x over previous
//
#include <hip/hip_runtime.h>
#include <hip/hip_bf16.h>

// Problem constants
#define T_ 8192
#define H_ 64
#define X_ 128
#define C_ 128   // chunks
#define L_ 64    // chunk length
#define MS 68    // LDS matrix row stride (floats); 68*4 B rows stay 16B-aligned

// workspace float offsets
#define OFF_P   (T_ * H_)              // P[13][4096]: A^(2^s), s=0..12
#define OFF_HS  (OFF_P + 13 * 4096)    // hstart[128][64]
#define OFF_G   (OFF_HS + C_ * H_)     // G[64][4096]: A^(i+1)

// ---------------------------------------------------------------------------
__device__ __forceinline__ void pin_row(float* arow) {
#pragma unroll
    for (int q = 0; q < 64; ++q) asm volatile("" : "+v"(arow[q]));
}

// y = arow . vec + init   (vec read via 16 same-address float4 -> broadcast)
__device__ __forceinline__ float mv64(const float* arow, const float* vec, float init) {
    const float4* h4 = (const float4*)vec;
    float a0 = init, a1 = 0.f, a2 = 0.f, a3 = 0.f;
#pragma unroll
    for (int q = 0; q < 16; ++q) {
        float4 hv = h4[q];
        a0 = fmaf(arow[4 * q + 0], hv.x, a0);
        a1 = fmaf(arow[4 * q + 1], hv.y, a1);
        a2 = fmaf(arow[4 * q + 2], hv.z, a2);
        a3 = fmaf(arow[4 * q + 3], hv.w, a3);
    }
    return (a0 + a1) + (a2 + a3);
}

// row `lane` of A = 0.9 I + 0.1 A_raw from global (coalesced)
__device__ __forceinline__ void load_arow_A(const float* __restrict__ A_raw,
                                            int lane, float* arow) {
    const float4* a4 = (const float4*)(A_raw + lane * H_);
#pragma unroll
    for (int q = 0; q < 16; ++q) {
        float4 t4 = a4[q];
        arow[4 * q + 0] = 0.1f * t4.x;
        arow[4 * q + 1] = 0.1f * t4.y;
        arow[4 * q + 2] = 0.1f * t4.z;
        arow[4 * q + 3] = 0.1f * t4.w;
    }
#pragma unroll
    for (int q = 0; q < 64; ++q) arow[q] += (q == lane) ? 0.9f : 0.0f;
    pin_row(arow);
}

// row `lane` of a row-major [64][64] global matrix
__device__ __forceinline__ void load_row_g(const float* __restrict__ M,
                                           int lane, float* arow) {
    const float4* a4 = (const float4*)(M + lane * H_);
#pragma unroll
    for (int q = 0; q < 16; ++q) {
        float4 t4 = a4[q];
        arow[4 * q + 0] = t4.x;
        arow[4 * q + 1] = t4.y;
        arow[4 * q + 2] = t4.z;
        arow[4 * q + 3] = t4.w;
    }
    pin_row(arow);
}

// row `lane` of an LDS matrix with stride MS
__device__ __forceinline__ void load_row_lds(const float* M, int lane, float* arow) {
    const float4* a4 = (const float4*)(M + lane * MS);
#pragma unroll
    for (int q = 0; q < 16; ++q) {
        float4 t4 = a4[q];
        arow[4 * q + 0] = t4.x;
        arow[4 * q + 1] = t4.y;
        arow[4 * q + 2] = t4.z;
        arow[4 * q + 3] = t4.w;
    }
    pin_row(arow);
}

// Block-wide (1024 thr) 64x64 matmul in LDS: Md = Ma * Mb (Md distinct from
// Ma,Mb buffers); optional row-major global store. Ends with __syncthreads.
__device__ __forceinline__ void mm64(const float* Ma, const float* Mb, float* Md,
                                     float* gout, int tid) {
    const int r = tid >> 4, c0 = (tid & 15) * 4;
    float a0 = 0.f, a1 = 0.f, a2 = 0.f, a3 = 0.f;
    for (int k = 0; k < H_; ++k) {
        const float av = Ma[r * MS + k];
        const float4 bv = *(const float4*)(Mb + k * MS + c0);
        a0 = fmaf(av, bv.x, a0);
        a1 = fmaf(av, bv.y, a1);
        a2 = fmaf(av, bv.z, a2);
        a3 = fmaf(av, bv.w, a3);
    }
    Md[r * MS + c0 + 0] = a0;
    Md[r * MS + c0 + 1] = a1;
    Md[r * MS + c0 + 2] = a2;
    Md[r * MS + c0 + 3] = a3;
    if (gout) {
        gout[r * H_ + c0 + 0] = a0;
        gout[r * H_ + c0 + 1] = a1;
        gout[r * H_ + c0 + 2] = a2;
        gout[r * H_ + c0 + 3] = a3;
    }
    __syncthreads();
}

// One doubling pass over 64 chunk rows: dst[i] = src[i] + M*src[i-dist]
// (i>=dist) else copy. Wave w handles rows {w, w+16, w+32, w+48}.
__device__ __forceinline__ void do_pass(const float* arow, const float (*src)[H_],
                                        float (*dst)[H_], int dist, int w, int lane) {
#pragma unroll
    for (int r = 0; r < 4; ++r) {
        const int i = w + 16 * r;
        if (i >= dist)
            dst[i][lane] = mv64(arow, src[i - dist], src[i][lane]);
        else
            dst[i][lane] = src[i][lane];
    }
}

// ---------------------------------------------------------------------------
// K1: blocks 0..127: bproj of own chunk -> LDS, then interleaved
//     {doubling pass, squaring} -> full chunk-local prefix d -> global.
//     block 128: export P[s] = A^(2^s), s=0..12.
// ---------------------------------------------------------------------------
__global__ __launch_bounds__(1024) void k_chunks(
        const float* __restrict__ x, const float* __restrict__ A_raw,
        const float* __restrict__ B, const float* __restrict__ c,
        float* __restrict__ ws) {
    __shared__ __align__(16) float M1[H_ * MS];
    __shared__ __align__(16) float M2[H_ * MS];
    __shared__ __align__(16) float dbuf[2][L_][H_];
    const int tid = threadIdx.x, lane = tid & 63, w = tid >> 6;
    float* d_pref = ws;
    float* P = ws + OFF_P;

    if (blockIdx.x == C_) {
        // ---- power block: P[s] = A^(2^s) ----
        for (int idx = tid; idx < H_ * H_; idx += 1024) {
            const int r = idx >> 6, k = idx & 63;
            const float val = 0.1f * A_raw[idx] + ((r == k) ? 0.9f : 0.0f);
            M1[r * MS + k] = val;
            P[idx] = val;
        }
        __syncthreads();
        float* src = M1;
        float* dst = M2;
        for (int s = 1; s <= 12; ++s) {
            mm64(src, src, dst, P + s * 4096, tid);  // dst = src*src  (FIXED)
            float* t = src; src = dst; dst = t;
        }
        return;
    }

    const int cid = blockIdx.x;
    // ---- b projection into dbuf[0] (wave w -> rows 4w..4w+3) ----
    {
        const float cc = c[lane];
        float acc[4] = {cc, cc, cc, cc};
        const float* Brow = B + lane * X_;
        const int t0 = cid * L_ + w * 4;
#pragma unroll
        for (int kc = 0; kc < 4; ++kc) {
            float4 br[8];
            const float4* b4 = (const float4*)(Brow + kc * 32);
#pragma unroll
            for (int q = 0; q < 8; ++q) br[q] = b4[q];
#pragma unroll
            for (int r = 0; r < 4; ++r) {
                const float4* xr = (const float4*)(x + (size_t)(t0 + r) * X_ + kc * 32);
#pragma unroll
                for (int q = 0; q < 8; ++q) {
                    float4 xv = xr[q];
                    acc[r] = fmaf(br[q].x, xv.x, acc[r]);
                    acc[r] = fmaf(br[q].y, xv.y, acc[r]);
                    acc[r] = fmaf(br[q].z, xv.z, acc[r]);
                    acc[r] = fmaf(br[q].w, xv.w, acc[r]);
                }
            }
        }
#pragma unroll
        for (int r = 0; r < 4; ++r) dbuf[0][w * 4 + r][lane] = acc[r];
    }
    // ---- load A into M1 (for local squarings) ----
    for (int idx = tid; idx < H_ * H_; idx += 1024) {
        const int r = idx >> 6, k = idx & 63;
        M1[r * MS + k] = 0.1f * A_raw[idx] + ((r == k) ? 0.9f : 0.0f);
    }
    __syncthreads();

    // ---- interleaved: pass(dist), then square for next pass ----
    {
        float arow[64];
        load_arow_A(A_raw, lane, arow);
        do_pass(arow, dbuf[0], dbuf[1], 1, w, lane);
        mm64(M1, M1, M2, nullptr, tid);            // M2 = A^2 (ends in barrier)
        load_row_lds(M2, lane, arow);
        do_pass(arow, dbuf[1], dbuf[0], 2, w, lane);
        mm64(M2, M2, M1, nullptr, tid);            // M1 = A^4
        load_row_lds(M1, lane, arow);
        do_pass(arow, dbuf[0], dbuf[1], 4, w, lane);
        mm64(M1, M1, M2, nullptr, tid);            // M2 = A^8
        load_row_lds(M2, lane, arow);
        do_pass(arow, dbuf[1], dbuf[0], 8, w, lane);
        mm64(M2, M2, M1, nullptr, tid);            // M1 = A^16
        load_row_lds(M1, lane, arow);
        do_pass(arow, dbuf[0], dbuf[1], 16, w, lane);
        mm64(M1, M1, M2, nullptr, tid);            // M2 = A^32
        load_row_lds(M2, lane, arow);
        do_pass(arow, dbuf[1], dbuf[0], 32, w, lane);
        __syncthreads();
    }
    // ---- write d (full chunk-local prefix) ----
    for (int idx = tid; idx < L_ * H_; idx += 1024)
        d_pref[(size_t)cid * L_ * H_ + idx] = dbuf[0][idx >> 6][idx & 63];
}

// ---------------------------------------------------------------------------
// K2: block 0: chunk-level doubling scan over u = [h0, v_0..v_126] with
//     Q^(2^k) = P[6+k] -> hstart[c] = s_c.
//     blocks 1..64: G_n = A^n by binary product over P[0..6] -> Gg[n-1].
// ---------------------------------------------------------------------------
__global__ __launch_bounds__(1024) void k_scan_g(
        const float* __restrict__ h0, float* __restrict__ ws) {
    __shared__ __align__(16) float smem[2 * C_ * H_];  // 64 KB
    const int tid = threadIdx.x, lane = tid & 63, w = tid >> 6;
    const float* d_pref = ws;
    const float* P = ws + OFF_P;
    float* hstart = ws + OFF_HS;
    float* Gg = ws + OFF_G;

    if (blockIdx.x == 0) {
        float (*sb0)[H_] = (float (*)[H_])smem;
        float (*sb1)[H_] = (float (*)[H_])(smem + C_ * H_);
        for (int idx = tid; idx < C_ * H_; idx += 1024) {
            const int row = idx >> 6, e = idx & 63;
            sb0[row][e] = (row == 0)
                ? h0[e]
                : d_pref[(size_t)(row - 1) * L_ * H_ + 63 * H_ + e];
        }
        __syncthreads();
        float (*src)[H_] = sb0;
        float (*dst)[H_] = sb1;
#pragma unroll
        for (int k = 0; k < 7; ++k) {
            const int dist = 1 << k;
            float arow[64];
            load_row_g(P + (6 + k) * 4096, lane, arow);
#pragma unroll
            for (int r = 0; r < 8; ++r) {
                const int i = w + 16 * r;
                if (i >= dist)
                    dst[i][lane] = mv64(arow, src[i - dist], src[i][lane]);
                else
                    dst[i][lane] = src[i][lane];
            }
            __syncthreads();
            float (*t)[H_] = src; src = dst; dst = t;
        }
        for (int idx = tid; idx < C_ * H_; idx += 1024)
            hstart[idx] = src[idx >> 6][idx & 63];
    } else {
        // G block: n = blockIdx.x in 1..64 ; Gg[n-1] = A^n
        float* Mp = smem;                 // product
        float* Mf = smem + H_ * MS;       // factor
        float* Mo = smem + 2 * H_ * MS;   // temp
        const int n = blockIdx.x;
        const int j0 = __ffs(n) - 1;
        for (int idx = tid; idx < H_ * H_; idx += 1024)
            Mp[(idx >> 6) * MS + (idx & 63)] = P[j0 * 4096 + idx];
        __syncthreads();
        for (int j = j0 + 1; j < 7; ++j) {
            if (!((n >> j) & 1)) continue;
            for (int idx = tid; idx < H_ * H_; idx += 1024)
                Mf[(idx >> 6) * MS + (idx & 63)] = P[j * 4096 + idx];
            __syncthreads();
            mm64(Mf, Mp, Mo, nullptr, tid);   // Mo = A^(2^j) * product
            float* t = Mp; Mp = Mo; Mo = t;
        }
        for (int idx = tid; idx < H_ * H_; idx += 1024)
            Gg[(size_t)(n - 1) * 4096 + idx] = Mp[(idx >> 6) * MS + (idx & 63)];
    }
}

// ---------------------------------------------------------------------------
// K3: block i (0..63): out[c*64+i][:] = G_i * s_c + d[c][i][:] for all c.
// ---------------------------------------------------------------------------
__global__ __launch_bounds__(1024) void k_out(
        float* __restrict__ out, const float* __restrict__ ws) {
    __shared__ __align__(16) float S[C_][H_];
    const int tid = threadIdx.x, lane = tid & 63, w = tid >> 6;
    const float* d_pref = ws;
    const float* hstart = ws + OFF_HS;
    const float* Gg = ws + OFF_G;
    const int i = blockIdx.x;

    for (int idx = tid; idx < C_ * H_; idx += 1024)
        S[idx >> 6][idx & 63] = hstart[idx];
    float arow[64];
    load_row_g(Gg + (size_t)i * 4096, lane, arow);
    __syncthreads();

#pragma unroll
    for (int r = 0; r < 8; ++r) {
        const int cc = w + 16 * r;
        const float dinit = d_pref[(size_t)cc * L_ * H_ + i * H_ + lane];
        out[((size_t)cc * L_ + i) * H_ + lane] = mv64(arow, S[cc], dinit);
    }
}

extern "C" void kernel_launch(void* const* d_in, const int* in_sizes, int n_in,
                              void* d_out, int out_size, void* d_ws, size_t ws_size,
                              hipStream_t stream) {
    const float* x     = (const float*)d_in[0];  // [T, X]
    const float* h0    = (const float*)d_in[1];  // [H]
    const float* A_raw = (const float*)d_in[2];  // [H, H]
    const float* B     = (const float*)d_in[3];  // [H, X]
    const float* c     = (const float*)d_in[4];  // [H]
    float* out = (float*)d_out;                  // [T, H]
    float* ws  = (float*)d_ws;

    k_chunks<<<C_ + 1, 1024, 0, stream>>>(x, A_raw, B, c, ws);
    k_scan_g<<<65,     1024, 0, stream>>>(h0, ws);
    k_out   <<<64,     1024, 0, stream>>>(out, ws);
}